// Round 6
// baseline (823.393 us; speedup 1.0000x reference)
//
#include <hip/hip_runtime.h>
#include <hip/hip_fp16.h>

#define T_SEQ 4096
#define NBATCH 4
#define EDIM 1024
#define ADIM 1024
#define MTOT (NBATCH * T_SEQ)  // 16384

typedef _Float16 f16x8 __attribute__((ext_vector_type(8)));
typedef float f32x4 __attribute__((ext_vector_type(4)));

// Stage one 128x32 f16 tile into LDS in subtile layout:
//   element(row, k) -> LDS f16 index ((row>>4)*4 + (k>>3))*128 + (row&15)*8 + (k&7)
// global_load_lds writes linearly (wave base + lane*16B); each 16-row subtile
// is 512 f16. The global SOURCE is permuted: lane supplies
// (row = rb*16 + (lane&15), kchunk = lane>>4).
// Fragment reads are then 64 lanes x 16B fully linear -> zero bank conflicts.
#define STAGE(SRC, LD, LDSARR)                                               \
  {                                                                          \
    _Pragma("unroll") for (int t = 0; t < 2; ++t) {                          \
      const int rb = w * 2 + t;                                              \
      const _Float16* gsrc =                                                 \
          (SRC) + (size_t)(rb * 16 + (lane & 15)) * (LD) + (lane >> 4) * 8;  \
      __builtin_amdgcn_global_load_lds(                                      \
          (const __attribute__((address_space(1))) void*)gsrc,               \
          (__attribute__((address_space(3))) void*)&LDSARR[rb * 512], 16,    \
          0, 0);                                                             \
    }                                                                        \
  }

#define FRAG(LDSARR, B4, G) (*(const f16x8*)&LDSARR[((B4) * 4 + (G)) * 128 + lr * 8])

// ---------------- Kernel 0: cast X to f16 ----------------
__global__ __launch_bounds__(256) void cast_x(const float* __restrict__ X,
                                              _Float16* __restrict__ Xh) {
  const size_t i = ((size_t)blockIdx.x * 256 + threadIdx.x) * 8;
  float4 a = ((const float4*)(X + i))[0];
  float4 b = ((const float4*)(X + i))[1];
  f16x8 o = {(_Float16)a.x, (_Float16)a.y, (_Float16)a.z, (_Float16)a.w,
             (_Float16)b.x, (_Float16)b.y, (_Float16)b.z, (_Float16)b.w};
  *(f16x8*)(Xh + i) = o;
}

// ---------------- Kernel 1: cast + transpose weights to f16 ----------------
__global__ __launch_bounds__(256) void cast_transpose_w(
    const float* __restrict__ Wk, const float* __restrict__ Wq,
    const float* __restrict__ Wv, _Float16* __restrict__ Wt) {
  __shared__ float tile[32][33];
  const int z = blockIdx.z;
  const float* W = (z == 0) ? Wk : (z == 1) ? Wq : Wv;
  const int n0 = blockIdx.x * 32, k0 = blockIdx.y * 32;
  const int tx = threadIdx.x, ty = threadIdx.y;  // block (32,8)
#pragma unroll
  for (int yy = 0; yy < 32; yy += 8)
    tile[ty + yy][tx] = W[(size_t)(k0 + ty + yy) * ADIM + n0 + tx];
  __syncthreads();
  _Float16* out = Wt + (size_t)z * EDIM * ADIM;
#pragma unroll
  for (int yy = 0; yy < 32; yy += 8)
    out[(size_t)(n0 + ty + yy) * EDIM + k0 + tx] = (_Float16)tile[tx][ty + yy];
}

// ---------------- Kernel 2: QKV projection GEMM ----------------
__global__ __launch_bounds__(256) void gemm_qkv(
    const _Float16* __restrict__ Xh, const _Float16* __restrict__ Wt,
    _Float16* __restrict__ Qb, _Float16* __restrict__ Kb,
    _Float16* __restrict__ Vt) {
  const int z = blockIdx.z;
  const _Float16* Bt = Wt + (size_t)z * EDIM * ADIM;
  __shared__ __align__(16) _Float16 Al[4096];
  __shared__ __align__(16) _Float16 Bl[4096];
  const int tid = threadIdx.x;
  const int lane = tid & 63, w = tid >> 6;
  const int wm = w >> 1, wn = w & 1;
  const int lr = lane & 15, g = lane >> 4;
  // XCD-aware bijective swizzle, n-fastest order (1024 blocks, 1024%8==0)
  const int h = blockIdx.y * gridDim.x + blockIdx.x;
  const int orig = (h & 7) * 128 + (h >> 3);
  const int m0 = (orig >> 3) * 128, n0 = (orig & 7) * 128;

  f32x4 acc[4][4] = {};

  for (int k0 = 0; k0 < EDIM; k0 += 32) {
    STAGE(Xh + (size_t)m0 * EDIM + k0, EDIM, Al);
    STAGE(Bt + (size_t)n0 * EDIM + k0, EDIM, Bl);
    __syncthreads();
    f16x8 af[4], bf[4];
#pragma unroll
    for (int i = 0; i < 4; i++) af[i] = FRAG(Al, wm * 4 + i, g);
#pragma unroll
    for (int j = 0; j < 4; j++) bf[j] = FRAG(Bl, wn * 4 + j, g);
#pragma unroll
    for (int i = 0; i < 4; i++)
#pragma unroll
      for (int j = 0; j < 4; j++)
        acc[i][j] = __builtin_amdgcn_mfma_f32_16x16x32_f16(af[i], bf[j], acc[i][j], 0, 0, 0);
    __syncthreads();
  }

#pragma unroll
  for (int i = 0; i < 4; i++)
#pragma unroll
    for (int j = 0; j < 4; j++)
#pragma unroll
      for (int r = 0; r < 4; r++) {
        const int row = m0 + wm * 64 + i * 16 + 4 * g + r;
        const int col = n0 + wn * 64 + j * 16 + lr;
        const _Float16 hv = (_Float16)acc[i][j][r];
        if (z == 0)
          Kb[(size_t)row * ADIM + col] = hv;
        else if (z == 1)
          Qb[(size_t)row * ADIM + col] = hv;
        else {
          const int b = row >> 12, tt = row & 4095;
          Vt[((size_t)b * ADIM + col) * T_SEQ + tt] = hv;
        }
      }
}

// ---------------- Kernel 3: S = Q K^T (lower-tri blocks only) ----------------
__global__ __launch_bounds__(256) void gemm_sqk(
    const _Float16* __restrict__ Qb, const _Float16* __restrict__ Kb,
    _Float16* __restrict__ Sb) {
  __shared__ __align__(16) _Float16 Al[4096];
  __shared__ __align__(16) _Float16 Bl[4096];
  const int b = blockIdx.y;
  const int tid = threadIdx.x;
  const int lane = tid & 63, w = tid >> 6;
  const int wm = w >> 1, wn = w & 1;
  const int lr = lane & 15, g = lane >> 4;
  // 528 lower-tri blocks, XCD swizzle (528/8 = 66), bi-major bj-fastest
  const int h = blockIdx.x;
  const int orig = (h & 7) * 66 + (h >> 3);
  int bi = (int)((sqrtf(8.f * orig + 1.f) - 1.f) * 0.5f);
  while ((bi + 1) * (bi + 2) / 2 <= orig) ++bi;
  while (bi * (bi + 1) / 2 > orig) --bi;
  const int bj = orig - bi * (bi + 1) / 2;
  const int m0 = bi * 128, n0 = bj * 128;
  const _Float16* A = Qb + (size_t)b * T_SEQ * ADIM;
  const _Float16* B = Kb + (size_t)b * T_SEQ * ADIM;

  f32x4 acc[4][4] = {};

  for (int k0 = 0; k0 < ADIM; k0 += 32) {
    STAGE(A + (size_t)m0 * ADIM + k0, ADIM, Al);
    STAGE(B + (size_t)n0 * ADIM + k0, ADIM, Bl);
    __syncthreads();
    f16x8 af[4], bf[4];
#pragma unroll
    for (int i = 0; i < 4; i++) af[i] = FRAG(Al, wm * 4 + i, g);
#pragma unroll
    for (int j = 0; j < 4; j++) bf[j] = FRAG(Bl, wn * 4 + j, g);
#pragma unroll
    for (int i = 0; i < 4; i++)
#pragma unroll
      for (int j = 0; j < 4; j++)
        acc[i][j] = __builtin_amdgcn_mfma_f32_16x16x32_f16(af[i], bf[j], acc[i][j], 0, 0, 0);
    __syncthreads();
  }

  _Float16* Srow = Sb + (size_t)b * T_SEQ * T_SEQ;
#pragma unroll
  for (int i = 0; i < 4; i++)
#pragma unroll
    for (int j = 0; j < 4; j++)
#pragma unroll
      for (int r = 0; r < 4; r++) {
        const int row = m0 + wm * 64 + i * 16 + 4 * g + r;
        const int col = n0 + wn * 64 + j * 16 + lr;
        Srow[(size_t)row * T_SEQ + col] = (_Float16)acc[i][j][r];
      }
}

// ---------------- Kernel 4: row softmax (in place, causal mask) ----------------
__global__ __launch_bounds__(512) void softmax_rows(_Float16* __restrict__ S) {
  const int i = blockIdx.x, b = blockIdx.y;
  const int padded = ((i >> 7) + 1) << 7;
  const int tid = threadIdx.x;
  const int lane = tid & 63, w = tid >> 6;
  const int j0 = tid * 8;
  const bool active = j0 < padded;
  _Float16* row = S + ((size_t)b * T_SEQ + i) * T_SEQ;
  const float sm_scale = 0.03125f;  // 1/sqrt(1024)

  float v[8];
  float m = -1e30f;
  if (active) {
    f16x8 x = *(const f16x8*)(row + j0);
#pragma unroll
    for (int jj = 0; jj < 8; jj++) {
      const float sv = (j0 + jj <= i) ? (float)x[jj] * sm_scale : -1e30f;
      v[jj] = sv;
      m = fmaxf(m, sv);
    }
  } else {
#pragma unroll
    for (int jj = 0; jj < 8; jj++) v[jj] = -1e30f;
  }
#pragma unroll
  for (int off = 1; off < 64; off <<= 1) m = fmaxf(m, __shfl_xor(m, off));
  __shared__ float redm[8], reds[8];
  if (lane == 0) redm[w] = m;
  __syncthreads();
#pragma unroll
  for (int ww = 0; ww < 8; ww++) m = fmaxf(m, redm[ww]);

  float s = 0.f;
#pragma unroll
  for (int jj = 0; jj < 8; jj++) {
    v[jj] = __expf(v[jj] - m);
    s += v[jj];
  }
#pragma unroll
  for (int off = 1; off < 64; off <<= 1) s += __shfl_xor(s, off);
  if (lane == 0) reds[w] = s;
  __syncthreads();
  s = 0.f;
#pragma unroll
  for (int ww = 0; ww < 8; ww++) s += reds[ww];
  const float inv = 1.f / s;

  if (active) {
    f16x8 o;
#pragma unroll
    for (int jj = 0; jj < 8; jj++) o[jj] = (_Float16)(v[jj] * inv);
    *(f16x8*)(row + j0) = o;
  }
}

// ---------------- Kernel 5: O = P V (causal: variable K extent) ----------------
__global__ __launch_bounds__(256) void gemm_pv(
    const _Float16* __restrict__ Pb, const _Float16* __restrict__ Vt,
    float* __restrict__ Out) {
  __shared__ __align__(16) _Float16 Al[4096];
  __shared__ __align__(16) _Float16 Bl[4096];
  const int b = blockIdx.y;
  const int tid = threadIdx.x;
  const int lane = tid & 63, w = tid >> 6;
  const int wm = w >> 1, wn = w & 1;
  const int lr = lane & 15, g = lane >> 4;
  // 256 blocks/batch, XCD swizzle, n-fastest
  const int h = blockIdx.x;
  const int orig = (h & 7) * 32 + (h >> 3);
  const int by = orig >> 3, bx = orig & 7;
  const int m0 = by * 128, n0 = bx * 128;
  const int kmax = (by + 1) * 128;
  const _Float16* A = Pb + (size_t)b * T_SEQ * T_SEQ;  // lda = T_SEQ
  const _Float16* B = Vt + (size_t)b * ADIM * T_SEQ;   // ldb = T_SEQ

  f32x4 acc[4][4] = {};

  for (int k0 = 0; k0 < kmax; k0 += 32) {
    STAGE(A + (size_t)m0 * T_SEQ + k0, T_SEQ, Al);
    STAGE(B + (size_t)n0 * T_SEQ + k0, T_SEQ, Bl);
    __syncthreads();
    f16x8 af[4], bf[4];
#pragma unroll
    for (int i = 0; i < 4; i++) af[i] = FRAG(Al, wm * 4 + i, g);
#pragma unroll
    for (int j = 0; j < 4; j++) bf[j] = FRAG(Bl, wn * 4 + j, g);
#pragma unroll
    for (int i = 0; i < 4; i++)
#pragma unroll
      for (int j = 0; j < 4; j++)
        acc[i][j] = __builtin_amdgcn_mfma_f32_16x16x32_f16(af[i], bf[j], acc[i][j], 0, 0, 0);
    __syncthreads();
  }

#pragma unroll
  for (int i = 0; i < 4; i++)
#pragma unroll
    for (int j = 0; j < 4; j++)
#pragma unroll
      for (int r = 0; r < 4; r++) {
        const int row = m0 + wm * 64 + i * 16 + 4 * g + r;
        const int col = n0 + wn * 64 + j * 16 + lr;
        Out[((size_t)b * T_SEQ + row) * ADIM + col] = acc[i][j][r];
      }
}

// ---------------- launch ----------------
extern "C" void kernel_launch(void* const* d_in, const int* in_sizes, int n_in,
                              void* d_out, int out_size, void* d_ws, size_t ws_size,
                              hipStream_t stream) {
  const float* X = (const float*)d_in[0];
  const float* Wk = (const float*)d_in[1];
  const float* Wq = (const float*)d_in[2];
  const float* Wv = (const float*)d_in[3];
  float* Out = (float*)d_out;

  char* ws = (char*)d_ws;
  const size_t WT_BYTES = (size_t)3 * EDIM * ADIM * 2;  // 6 MB
  const size_t MAT_BYTES = (size_t)MTOT * ADIM * 2;     // 32 MB each
  _Float16* Wt = (_Float16*)ws;
  _Float16* Kb = (_Float16*)(ws + WT_BYTES);
  _Float16* Qb = (_Float16*)(ws + WT_BYTES + MAT_BYTES);
  _Float16* Vt = (_Float16*)(ws + WT_BYTES + 2 * MAT_BYTES);
  _Float16* Xh = (_Float16*)(ws + WT_BYTES + 3 * MAT_BYTES);  // dead after gemm_qkv
  _Float16* Sb = (_Float16*)(ws + WT_BYTES + 3 * MAT_BYTES);  // overlaps Xh, 128 MB

  cast_x<<<dim3(MTOT * EDIM / 2048), dim3(256), 0, stream>>>(X, Xh);
  cast_transpose_w<<<dim3(32, 32, 3), dim3(32, 8), 0, stream>>>(Wk, Wq, Wv, Wt);
  gemm_qkv<<<dim3(8, 128, 3), dim3(256), 0, stream>>>(Xh, Wt, Qb, Kb, Vt);
  gemm_sqk<<<dim3(528, NBATCH), dim3(256), 0, stream>>>(Qb, Kb, Sb);
  softmax_rows<<<dim3(T_SEQ, NBATCH), dim3(512), 0, stream>>>(Sb);
  gemm_pv<<<dim3(256, NBATCH), dim3(256), 0, stream>>>(Sb, Vt, Out);
}

// Round 7
// 694.970 us; speedup vs baseline: 1.1848x; 1.1848x over previous
//
#include <hip/hip_runtime.h>
#include <hip/hip_fp16.h>

#define T_SEQ 4096
#define NBATCH 4
#define EDIM 1024
#define ADIM 1024
#define MTOT (NBATCH * T_SEQ)  // 16384

typedef _Float16 f16x8 __attribute__((ext_vector_type(8)));
typedef float f32x4 __attribute__((ext_vector_type(4)));

// Stage one 128x32 f16 tile into LDS in subtile layout:
//   element(row, k) -> LDS f16 index ((row>>4)*4 + (k>>3))*128 + (row&15)*8 + (k&7)
// global_load_lds writes linearly (wave base + lane*16B); each 16-row subtile
// is 512 f16. The global SOURCE is permuted: lane supplies
// (row = rb*16 + (lane&15), kchunk = lane>>4).
// Fragment reads are then 64 lanes x 16B fully linear -> zero bank conflicts.
#define STAGE(SRC, LD, LDSARR)                                               \
  {                                                                          \
    _Pragma("unroll") for (int t = 0; t < 2; ++t) {                          \
      const int rb = w * 2 + t;                                              \
      const _Float16* gsrc =                                                 \
          (SRC) + (size_t)(rb * 16 + (lane & 15)) * (LD) + (lane >> 4) * 8;  \
      __builtin_amdgcn_global_load_lds(                                      \
          (const __attribute__((address_space(1))) void*)gsrc,               \
          (__attribute__((address_space(3))) void*)&LDSARR[rb * 512], 16,    \
          0, 0);                                                             \
    }                                                                        \
  }

#define FRAG(LDSARR, B4, G) (*(const f16x8*)&LDSARR[((B4) * 4 + (G)) * 128 + lr * 8])

// ---------------- Kernel 0: cast X to f16 ----------------
__global__ __launch_bounds__(256) void cast_x(const float* __restrict__ X,
                                              _Float16* __restrict__ Xh) {
  const size_t i = ((size_t)blockIdx.x * 256 + threadIdx.x) * 8;
  float4 a = ((const float4*)(X + i))[0];
  float4 b = ((const float4*)(X + i))[1];
  f16x8 o = {(_Float16)a.x, (_Float16)a.y, (_Float16)a.z, (_Float16)a.w,
             (_Float16)b.x, (_Float16)b.y, (_Float16)b.z, (_Float16)b.w};
  *(f16x8*)(Xh + i) = o;
}

// ---------------- Kernel 1: cast + transpose weights to f16 ----------------
__global__ __launch_bounds__(256) void cast_transpose_w(
    const float* __restrict__ Wk, const float* __restrict__ Wq,
    const float* __restrict__ Wv, _Float16* __restrict__ Wt) {
  __shared__ float tile[32][33];
  const int z = blockIdx.z;
  const float* W = (z == 0) ? Wk : (z == 1) ? Wq : Wv;
  const int n0 = blockIdx.x * 32, k0 = blockIdx.y * 32;
  const int tx = threadIdx.x, ty = threadIdx.y;  // block (32,8)
#pragma unroll
  for (int yy = 0; yy < 32; yy += 8)
    tile[ty + yy][tx] = W[(size_t)(k0 + ty + yy) * ADIM + n0 + tx];
  __syncthreads();
  _Float16* out = Wt + (size_t)z * EDIM * ADIM;
#pragma unroll
  for (int yy = 0; yy < 32; yy += 8)
    out[(size_t)(n0 + ty + yy) * EDIM + k0 + tx] = (_Float16)tile[tx][ty + yy];
}

// ---------------- Kernel 2: QKV projection GEMM ----------------
__global__ __launch_bounds__(256) void gemm_qkv(
    const _Float16* __restrict__ Xh, const _Float16* __restrict__ Wt,
    _Float16* __restrict__ Qb, _Float16* __restrict__ Kb,
    _Float16* __restrict__ Vt) {
  const int z = blockIdx.z;
  const _Float16* Bt = Wt + (size_t)z * EDIM * ADIM;
  __shared__ __align__(16) _Float16 Al[4096];
  __shared__ __align__(16) _Float16 Bl[4096];
  const int tid = threadIdx.x;
  const int lane = tid & 63, w = tid >> 6;
  const int wm = w >> 1, wn = w & 1;
  const int lr = lane & 15, g = lane >> 4;
  // XCD-aware bijective swizzle, n-fastest order (1024 blocks, 1024%8==0)
  const int h = blockIdx.y * gridDim.x + blockIdx.x;
  const int orig = (h & 7) * 128 + (h >> 3);
  const int m0 = (orig >> 3) * 128, n0 = (orig & 7) * 128;

  f32x4 acc[4][4] = {};

  for (int k0 = 0; k0 < EDIM; k0 += 32) {
    STAGE(Xh + (size_t)m0 * EDIM + k0, EDIM, Al);
    STAGE(Bt + (size_t)n0 * EDIM + k0, EDIM, Bl);
    __syncthreads();
    f16x8 af[4], bf[4];
#pragma unroll
    for (int i = 0; i < 4; i++) af[i] = FRAG(Al, wm * 4 + i, g);
#pragma unroll
    for (int j = 0; j < 4; j++) bf[j] = FRAG(Bl, wn * 4 + j, g);
#pragma unroll
    for (int i = 0; i < 4; i++)
#pragma unroll
      for (int j = 0; j < 4; j++)
        acc[i][j] = __builtin_amdgcn_mfma_f32_16x16x32_f16(af[i], bf[j], acc[i][j], 0, 0, 0);
    __syncthreads();
  }

#pragma unroll
  for (int i = 0; i < 4; i++)
#pragma unroll
    for (int j = 0; j < 4; j++)
#pragma unroll
      for (int r = 0; r < 4; r++) {
        const int row = m0 + wm * 64 + i * 16 + 4 * g + r;
        const int col = n0 + wn * 64 + j * 16 + lr;
        const _Float16 hv = (_Float16)acc[i][j][r];
        if (z == 0)
          Kb[(size_t)row * ADIM + col] = hv;
        else if (z == 1)
          Qb[(size_t)row * ADIM + col] = hv;
        else {
          const int b = row >> 12, tt = row & 4095;
          Vt[((size_t)b * ADIM + col) * T_SEQ + tt] = hv;
        }
      }
}

// ---------------- Kernel 3: S = Q K^T (lower-tri blocks only) ----------------
__global__ __launch_bounds__(256) void gemm_sqk(
    const _Float16* __restrict__ Qb, const _Float16* __restrict__ Kb,
    _Float16* __restrict__ Sb) {
  __shared__ __align__(16) _Float16 Al[4096];
  __shared__ __align__(16) _Float16 Bl[4096];
  const int b = blockIdx.y;
  const int tid = threadIdx.x;
  const int lane = tid & 63, w = tid >> 6;
  const int wm = w >> 1, wn = w & 1;
  const int lr = lane & 15, g = lane >> 4;
  // 528 lower-tri blocks, XCD swizzle (528/8 = 66), bi-major bj-fastest
  const int h = blockIdx.x;
  const int orig = (h & 7) * 66 + (h >> 3);
  int bi = (int)((sqrtf(8.f * orig + 1.f) - 1.f) * 0.5f);
  while ((bi + 1) * (bi + 2) / 2 <= orig) ++bi;
  while (bi * (bi + 1) / 2 > orig) --bi;
  const int bj = orig - bi * (bi + 1) / 2;
  const int m0 = bi * 128, n0 = bj * 128;
  const _Float16* A = Qb + (size_t)b * T_SEQ * ADIM;
  const _Float16* B = Kb + (size_t)b * T_SEQ * ADIM;

  f32x4 acc[4][4] = {};

  for (int k0 = 0; k0 < ADIM; k0 += 32) {
    STAGE(A + (size_t)m0 * ADIM + k0, ADIM, Al);
    STAGE(B + (size_t)n0 * ADIM + k0, ADIM, Bl);
    __syncthreads();
    f16x8 af[4], bf[4];
#pragma unroll
    for (int i = 0; i < 4; i++) af[i] = FRAG(Al, wm * 4 + i, g);
#pragma unroll
    for (int j = 0; j < 4; j++) bf[j] = FRAG(Bl, wn * 4 + j, g);
#pragma unroll
    for (int i = 0; i < 4; i++)
#pragma unroll
      for (int j = 0; j < 4; j++)
        acc[i][j] = __builtin_amdgcn_mfma_f32_16x16x32_f16(af[i], bf[j], acc[i][j], 0, 0, 0);
    __syncthreads();
  }

  _Float16* Srow = Sb + (size_t)b * T_SEQ * T_SEQ;
#pragma unroll
  for (int i = 0; i < 4; i++)
#pragma unroll
    for (int j = 0; j < 4; j++)
#pragma unroll
      for (int r = 0; r < 4; r++) {
        const int row = m0 + wm * 64 + i * 16 + 4 * g + r;
        const int col = n0 + wn * 64 + j * 16 + lr;
        Srow[(size_t)row * T_SEQ + col] = (_Float16)acc[i][j][r];
      }
}

// ---------------- Kernel 4: row softmax (in place, causal mask) ----------------
__global__ __launch_bounds__(512) void softmax_rows(_Float16* __restrict__ S) {
  const int i = blockIdx.x, b = blockIdx.y;
  const int padded = ((i >> 7) + 1) << 7;
  const int tid = threadIdx.x;
  const int lane = tid & 63, w = tid >> 6;
  const int j0 = tid * 8;
  const bool active = j0 < padded;
  _Float16* row = S + ((size_t)b * T_SEQ + i) * T_SEQ;
  const float sm_scale = 0.03125f;  // 1/sqrt(1024)

  float v[8];
  float m = -1e30f;
  if (active) {
    f16x8 x = *(const f16x8*)(row + j0);
#pragma unroll
    for (int jj = 0; jj < 8; jj++) {
      const float sv = (j0 + jj <= i) ? (float)x[jj] * sm_scale : -1e30f;
      v[jj] = sv;
      m = fmaxf(m, sv);
    }
  } else {
#pragma unroll
    for (int jj = 0; jj < 8; jj++) v[jj] = -1e30f;
  }
#pragma unroll
  for (int off = 1; off < 64; off <<= 1) m = fmaxf(m, __shfl_xor(m, off));
  __shared__ float redm[8], reds[8];
  if (lane == 0) redm[w] = m;
  __syncthreads();
#pragma unroll
  for (int ww = 0; ww < 8; ww++) m = fmaxf(m, redm[ww]);

  float s = 0.f;
#pragma unroll
  for (int jj = 0; jj < 8; jj++) {
    v[jj] = __expf(v[jj] - m);
    s += v[jj];
  }
#pragma unroll
  for (int off = 1; off < 64; off <<= 1) s += __shfl_xor(s, off);
  if (lane == 0) reds[w] = s;
  __syncthreads();
  s = 0.f;
#pragma unroll
  for (int ww = 0; ww < 8; ww++) s += reds[ww];
  const float inv = 1.f / s;

  if (active) {
    f16x8 o;
#pragma unroll
    for (int jj = 0; jj < 8; jj++) o[jj] = (_Float16)(v[jj] * inv);
    *(f16x8*)(row + j0) = o;
  }
}

// ---------------- Kernel 5: O = P V, split-K (causal, balanced) ----------------
// Chunk K at 2048: c=0 -> K [0, min(kmax,2048)) stored to Out;
// c=1 (only by>=16) -> K [2048, kmax) stored f32 to Part (reused Qb region).
// 384 blocks/batch: h<128 -> {by=h>>3, c=0, bx=h&7};
// else idx=h-128 -> {by=16+(idx>>4), c=(idx>>3)&1, bx=idx&7}. Max 64 K-iters.
__global__ __launch_bounds__(256) void gemm_pv(
    const _Float16* __restrict__ Pb, const _Float16* __restrict__ Vt,
    float* __restrict__ Part, float* __restrict__ Out) {
  __shared__ __align__(16) _Float16 Al[4096];
  __shared__ __align__(16) _Float16 Bl[4096];
  const int b = blockIdx.y;
  const int tid = threadIdx.x;
  const int lane = tid & 63, w = tid >> 6;
  const int wm = w >> 1, wn = w & 1;
  const int lr = lane & 15, g = lane >> 4;
  // XCD swizzle over 384 blocks (384 = 8*48)
  const int h = blockIdx.x;
  const int orig = (h & 7) * 48 + (h >> 3);
  int by, c, bx;
  if (orig < 128) {
    by = orig >> 3; c = 0; bx = orig & 7;
  } else {
    const int idx = orig - 128;
    by = 16 + (idx >> 4); c = (idx >> 3) & 1; bx = idx & 7;
  }
  const int m0 = by * 128, n0 = bx * 128;
  const int kbeg = c * 2048;
  const int kmax = (by + 1) * 128;
  const int kend = (c == 0) ? (kmax < 2048 ? kmax : 2048) : kmax;
  const _Float16* A = Pb + (size_t)b * T_SEQ * T_SEQ;  // lda = T_SEQ
  const _Float16* B = Vt + (size_t)b * ADIM * T_SEQ;   // ldb = T_SEQ

  f32x4 acc[4][4] = {};

  for (int k0 = kbeg; k0 < kend; k0 += 32) {
    STAGE(A + (size_t)m0 * T_SEQ + k0, T_SEQ, Al);
    STAGE(B + (size_t)n0 * T_SEQ + k0, T_SEQ, Bl);
    __syncthreads();
    f16x8 af[4], bf[4];
#pragma unroll
    for (int i = 0; i < 4; i++) af[i] = FRAG(Al, wm * 4 + i, g);
#pragma unroll
    for (int j = 0; j < 4; j++) bf[j] = FRAG(Bl, wn * 4 + j, g);
#pragma unroll
    for (int i = 0; i < 4; i++)
#pragma unroll
      for (int j = 0; j < 4; j++)
        acc[i][j] = __builtin_amdgcn_mfma_f32_16x16x32_f16(af[i], bf[j], acc[i][j], 0, 0, 0);
    __syncthreads();
  }

#pragma unroll
  for (int i = 0; i < 4; i++)
#pragma unroll
    for (int j = 0; j < 4; j++)
#pragma unroll
      for (int r = 0; r < 4; r++) {
        const int row = m0 + wm * 64 + i * 16 + 4 * g + r;
        const int col = n0 + wn * 64 + j * 16 + lr;
        if (c == 0)
          Out[((size_t)b * T_SEQ + row) * ADIM + col] = acc[i][j][r];
        else
          Part[((size_t)b * 2048 + (row - 2048)) * ADIM + col] = acc[i][j][r];
      }
}

// ---------------- Kernel 6: Out[rows>=2048] += Part ----------------
__global__ __launch_bounds__(256) void reduce_pv(const float* __restrict__ Part,
                                                 float* __restrict__ Out) {
  const size_t id = (size_t)blockIdx.x * 256 + threadIdx.x;  // float4 index
  const int b = (int)(id >> 19);          // 2048*1024/4 = 524288 per batch
  const size_t rem = id & 524287;
  const size_t row2 = rem >> 8, coli = rem & 255;  // 256 float4 per row
  float4* o = (float4*)Out + ((size_t)(b * 4096 + 2048) + row2) * 256 + coli;
  const float4* p = (const float4*)Part + ((size_t)b * 2048 + row2) * 256 + coli;
  float4 ov = *o;
  const float4 pv = *p;
  ov.x += pv.x; ov.y += pv.y; ov.z += pv.z; ov.w += pv.w;
  *o = ov;
}

// ---------------- launch ----------------
extern "C" void kernel_launch(void* const* d_in, const int* in_sizes, int n_in,
                              void* d_out, int out_size, void* d_ws, size_t ws_size,
                              hipStream_t stream) {
  const float* X = (const float*)d_in[0];
  const float* Wk = (const float*)d_in[1];
  const float* Wq = (const float*)d_in[2];
  const float* Wv = (const float*)d_in[3];
  float* Out = (float*)d_out;

  char* ws = (char*)d_ws;
  const size_t WT_BYTES = (size_t)3 * EDIM * ADIM * 2;  // 6 MB
  const size_t MAT_BYTES = (size_t)MTOT * ADIM * 2;     // 32 MB each
  _Float16* Wt = (_Float16*)ws;
  _Float16* Kb = (_Float16*)(ws + WT_BYTES);
  _Float16* Qb = (_Float16*)(ws + WT_BYTES + MAT_BYTES);
  _Float16* Vt = (_Float16*)(ws + WT_BYTES + 2 * MAT_BYTES);
  _Float16* Xh = (_Float16*)(ws + WT_BYTES + 3 * MAT_BYTES);  // dead after gemm_qkv
  _Float16* Sb = (_Float16*)(ws + WT_BYTES + 3 * MAT_BYTES);  // overlaps Xh, 128 MB
  float* Part = (float*)Qb;  // Qb dead after gemm_sqk; 32 MB = 4*2048*1024 f32

  cast_x<<<dim3(MTOT * EDIM / 2048), dim3(256), 0, stream>>>(X, Xh);
  cast_transpose_w<<<dim3(32, 32, 3), dim3(32, 8), 0, stream>>>(Wk, Wq, Wv, Wt);
  gemm_qkv<<<dim3(8, 128, 3), dim3(256), 0, stream>>>(Xh, Wt, Qb, Kb, Vt);
  gemm_sqk<<<dim3(528, NBATCH), dim3(256), 0, stream>>>(Qb, Kb, Sb);
  softmax_rows<<<dim3(T_SEQ, NBATCH), dim3(512), 0, stream>>>(Sb);
  gemm_pv<<<dim3(384, NBATCH), dim3(256), 0, stream>>>(Sb, Vt, Part, Out);
  reduce_pv<<<dim3(NBATCH * 2048 * 1024 / 4 / 256), dim3(256), 0, stream>>>(Part, Out);
}